// Round 10
// baseline (320.695 us; speedup 1.0000x reference)
//
#include <hip/hip_runtime.h>
#include <hip/hip_bf16.h>
#include <math.h>

#define NT 8192
#define HD 768
#define ID 3072
#define NE 8
#define BK 32
#define MAXB 136    // >= sum_e ceil(cnt_e/128); 136 = 8*17 (bijective XCD swizzle)
#define ASZ (128 * BK)
#define BSZ (128 * BK)
#define RT_BLOCKS (NT / 32)                 // 256 router blocks
#define CONV_BLOCKS (NE * ID * HD / 4 / 256) // 18432 convert blocks

typedef __bf16 bf16x8 __attribute__((ext_vector_type(8)));
typedef float f32x4 __attribute__((ext_vector_type(4)));

__device__ __forceinline__ unsigned short f2bf(float f) {
    union { float f; unsigned u; } v; v.f = f;
    unsigned r = v.u + 0x7FFFu + ((v.u >> 16) & 1u);   // RNE
    return (unsigned short)(r >> 16);
}
__device__ __forceinline__ float bf2f(unsigned short b) {
    union { unsigned u; float f; } v; v.u = ((unsigned)b) << 16;
    return v.f;
}
// packed RNE f32x2 -> bf16x2 (single instruction)
__device__ __forceinline__ unsigned cvt_pk_bf16(float lo, float hi) {
    unsigned r;
    asm("v_cvt_pk_bf16_f32 %0, %1, %2" : "=v"(r) : "v"(lo), "v"(hi));
    return r;
}
// gelu(tanh form) == v * sigmoid(2u), 2u = c1*v + c2*v^3. 1 exp + 1 rcp.
__device__ __forceinline__ float gelu_s(float v) {
    float z = v * (1.5957691216057308f + 0.07135481283687945f * v * v);
    float e = __expf(-z);
    return v * __builtin_amdgcn_rcpf(1.0f + e);
}

// global->LDS direct copy, 16B/lane. LDS dest = wave-uniform base + lane*16.
__device__ __forceinline__ void gload16(const void* g, void* l) {
    auto* lds = reinterpret_cast<__attribute__((address_space(3))) unsigned int*>(
        reinterpret_cast<uintptr_t>(l));
    auto* gp = reinterpret_cast<const __attribute__((address_space(1))) unsigned int*>(
        reinterpret_cast<uintptr_t>(g));
    __builtin_amdgcn_global_load_lds(gp, lds, 16, 0, 0);
}

// Fused front: blocks [0,RT_BLOCKS) = router; rest = fp32->bf16 weight convert.
__global__ void k_front(const float* __restrict__ x, const float* __restrict__ rw,
                        const float4* __restrict__ w1, const float4* __restrict__ w2,
                        ushort4* __restrict__ w1b, ushort4* __restrict__ w2b,
                        ushort4* __restrict__ xb4, float* __restrict__ gates,
                        uchar2* __restrict__ choice) {
    __shared__ float rws[NE * HD];
    const int tid = threadIdx.x;
    if (blockIdx.x >= RT_BLOCKS) {
        int i = (blockIdx.x - RT_BLOCKS) * 256 + tid;
        float4 a = w1[i]; float4 b = w2[i];
        ushort4 ra, rb;
        ra.x = f2bf(a.x); ra.y = f2bf(a.y); ra.z = f2bf(a.z); ra.w = f2bf(a.w);
        rb.x = f2bf(b.x); rb.y = f2bf(b.y); rb.z = f2bf(b.z); rb.w = f2bf(b.w);
        w1b[i] = ra; w2b[i] = rb;
        return;
    }
    for (int i = tid; i < NE * HD / 4; i += 256)
        ((float4*)rws)[i] = ((const float4*)rw)[i];
    __syncthreads();
    const int wid = tid >> 6, lane = tid & 63;
    const float4* rws4 = (const float4*)rws;
    for (int it = 0; it < 8; ++it) {
        const int t = blockIdx.x * 32 + wid * 8 + it;
        const float4* xp4 = (const float4*)(x + (size_t)t * HD);
        float acc[NE];
#pragma unroll
        for (int e = 0; e < NE; e++) acc[e] = 0.f;
#pragma unroll
        for (int j = 0; j < HD / 256; j++) {
            float4 v = xp4[lane + 64 * j];
            ushort4 o;
            o.x = f2bf(v.x); o.y = f2bf(v.y); o.z = f2bf(v.z); o.w = f2bf(v.w);
            xb4[(size_t)t * (HD / 4) + lane + 64 * j] = o;
#pragma unroll
            for (int e = 0; e < NE; e++) {
                float4 w = rws4[e * (HD / 4) + lane + 64 * j];
                acc[e] += v.x * w.x + v.y * w.y + v.z * w.z + v.w * w.w;
            }
        }
#pragma unroll
        for (int e = 0; e < NE; e++)
            for (int off = 32; off; off >>= 1) acc[e] += __shfl_xor(acc[e], off);
        if (lane == 0) {
            float mx = acc[0];
#pragma unroll
            for (int e = 1; e < NE; e++) mx = fmaxf(mx, acc[e]);
            float p[NE], s = 0.f;
#pragma unroll
            for (int e = 0; e < NE; e++) { p[e] = __expf(acc[e] - mx); s += p[e]; }
            float inv = 1.f / s;
            int i1 = 0; float b1 = p[0];
#pragma unroll
            for (int e = 1; e < NE; e++) if (p[e] > b1) { b1 = p[e]; i1 = e; }
            int i2 = (i1 == 0) ? 1 : 0; float b2 = p[i2];
#pragma unroll
            for (int e = 0; e < NE; e++) if (e != i1 && p[e] > b2) { b2 = p[e]; i2 = e; }
            choice[t].x = (unsigned char)i1;
            choice[t].y = (unsigned char)i2;
            gates[2 * t] = b1 * inv;
            gates[2 * t + 1] = b2 * inv;
        }
    }
}

// Router phase 2: one block per expert; ballot/prefix-scan compaction. No atomics.
__global__ void k_scatter(const uchar2* __restrict__ choice,
                          int* __restrict__ lists, int* __restrict__ counts) {
    const int e = blockIdx.x;
    const int tid = threadIdx.x, wid = tid >> 6, lane = tid & 63;
    __shared__ int wtot[4];
    __shared__ int running;
    if (tid == 0) running = 0;
    __syncthreads();
    for (int t0 = 0; t0 < NT; t0 += 256) {
        const int t = t0 + tid;
        uchar2 c = choice[t];
        bool m1 = (c.x == e), m2 = (c.y == e);
        bool m = m1 || m2;
        int slot = m1 ? 2 * t : 2 * t + 1;
        unsigned long long mask = __ballot(m);
        int off = __popcll(mask & ((1ULL << lane) - 1ULL));
        if (lane == 0) wtot[wid] = __popcll(mask);
        __syncthreads();
        int base = running;
        for (int w = 0; w < wid; w++) base += wtot[w];
        if (m) lists[e * NT + base + off] = slot;
        __syncthreads();
        if (tid == 0) running += wtot[0] + wtot[1] + wtot[2] + wtot[3];
        __syncthreads();
    }
    if (tid == 0) counts[e] = running;
}

// Both GEMMs: one proven block template. 128x128 tile, 4 waves (wave tile 64x64),
// BK=32, 3 LDS buffers (48.5 KB -> 3 blocks/CU at 132 regs/wave = 12 waves/CU),
// depth-2 counted-vmcnt pipeline (4 gload16/wave/stage, wait vmcnt(4)).
// LDS rows 64 B; 16B-chunk c of row r stored at c ^ ((r>>1)&3): ds_read_b128
// 2-way bank aliasing (free), staging coalesced via pre-permuted global source.
// MFMA operand swap (b,a) -> D^T fragments -> packed uint2 epilogue stores
// via v_cvt_pk_bf16_f32. XCD swizzle bijective (gridDim.x = 136 = 8*17).

// GEMM1: h[slot] = gelu(x_gathered @ w1[e]^T). NK = HD/BK = 24.
__launch_bounds__(256, 3)
__global__ void k_gemm1(const unsigned short* __restrict__ xb, const unsigned short* __restrict__ w1b,
                        const int* __restrict__ lists, const int* __restrict__ counts,
                        unsigned short* __restrict__ hbuf) {
    const int bsw = (blockIdx.x & 7) * (MAXB >> 3) + (blockIdx.x >> 3);
    int e = -1, m0 = 0;
    {
        int s = 0;
#pragma unroll
        for (int q = 0; q < NE; q++) {
            int nb = (counts[q] + 127) >> 7;
            if (bsw >= s && bsw < s + nb) { e = q; m0 = (bsw - s) << 7; }
            s += nb;
        }
    }
    if (e < 0) return;
    const int cnt = counts[e];
    const int n0 = blockIdx.y * 128;
    __shared__ __align__(16) unsigned short As[3 * ASZ];
    __shared__ __align__(16) unsigned short Bs[3 * BSZ];
    __shared__ int slot_s[128];
    const int tid = threadIdx.x, lane = tid & 63, wid = tid >> 6;
    if (tid < 128) {
        int r = m0 + tid;
        slot_s[tid] = lists[e * NT + (r < cnt ? r : cnt - 1)];
    }
    __syncthreads();

    const int rsub = lane >> 2;
    const int sw = (((lane & 3) ^ ((rsub >> 1) & 3)) * 8);
    const int row0 = wid * 16 + rsub;
    const unsigned short* gA0 = xb + (size_t)(slot_s[row0] >> 1) * HD + sw;
    const unsigned short* gA1 = xb + (size_t)(slot_s[row0 + 64] >> 1) * HD + sw;
    const unsigned short* gB0 = w1b + ((size_t)e * ID + n0 + row0) * HD + sw;
    const unsigned short* gB1 = gB0 + (size_t)64 * HD;
    auto stage = [&](int bf) {
        gload16(gA0, As + bf * ASZ + wid * 512);       gA0 += BK;
        gload16(gA1, As + bf * ASZ + (wid + 4) * 512); gA1 += BK;
        gload16(gB0, Bs + bf * BSZ + wid * 512);       gB0 += BK;
        gload16(gB1, Bs + bf * BSZ + (wid + 4) * 512); gB1 += BK;
    };

    const int wr = wid >> 1, wc = wid & 1;
    const int l15 = lane & 15, l4 = lane >> 4;
    const int aBase = (wr * 64 + l15) * BK;
    const int bBase = (wc * 64 + l15) * BK;
    const int cs = (l4 ^ ((l15 >> 1) & 3)) * 8;

    f32x4 acc[4][4];
    f32x4 zero = {0.f, 0.f, 0.f, 0.f};
#pragma unroll
    for (int m = 0; m < 4; m++)
#pragma unroll
        for (int n = 0; n < 4; n++) acc[m][n] = zero;

    const int NK = HD / BK;      // 24
    stage(0); stage(1);
    int cur = 0, pf = 2;
    for (int kt = 0; kt < NK; ++kt) {
        if (kt + 1 < NK) asm volatile("s_waitcnt vmcnt(4)\ns_barrier" ::: "memory");
        else             asm volatile("s_waitcnt vmcnt(0)\ns_barrier" ::: "memory");
        if (kt + 2 < NK) { stage(pf); pf = (pf == 2) ? 0 : pf + 1; }
        const unsigned short* Ab = As + cur * ASZ;
        const unsigned short* Bb = Bs + cur * BSZ;
        bf16x8 a[4], b[4];
#pragma unroll
        for (int m = 0; m < 4; m++) a[m] = *(const bf16x8*)(Ab + aBase + m * 512 + cs);
#pragma unroll
        for (int n = 0; n < 4; n++) b[n] = *(const bf16x8*)(Bb + bBase + n * 512 + cs);
#pragma unroll
        for (int m = 0; m < 4; m++)
#pragma unroll
            for (int n = 0; n < 4; n++)
                acc[m][n] = __builtin_amdgcn_mfma_f32_16x16x32_bf16(b[n], a[m], acc[m][n], 0, 0, 0);
        cur = (cur == 2) ? 0 : cur + 1;
    }
    const int rj = l4 * 4;
#pragma unroll
    for (int m = 0; m < 4; m++) {
        int lr2 = wr * 64 + m * 16 + l15;
        if (m0 + lr2 < cnt) {
            int slot = slot_s[lr2];
            unsigned short* hp = hbuf + (size_t)slot * ID + n0 + wc * 64 + rj;
#pragma unroll
            for (int n = 0; n < 4; n++) {
                uint2 pk;
                pk.x = cvt_pk_bf16(gelu_s(acc[m][n][0]), gelu_s(acc[m][n][1]));
                pk.y = cvt_pk_bf16(gelu_s(acc[m][n][2]), gelu_s(acc[m][n][3]));
                *(uint2*)(hp + n * 16) = pk;
            }
        }
    }
}

// GEMM2: pout[slot] = gate[slot] * (h_gathered @ w2[e]^T). Same template, NK = 96.
__launch_bounds__(256, 3)
__global__ void k_gemm2(const unsigned short* __restrict__ hbuf, const unsigned short* __restrict__ w2b,
                        const int* __restrict__ lists, const int* __restrict__ counts,
                        const float* __restrict__ gates, unsigned short* __restrict__ pout) {
    const int bsw = (blockIdx.x & 7) * (MAXB >> 3) + (blockIdx.x >> 3);
    int e = -1, m0 = 0;
    {
        int s = 0;
#pragma unroll
        for (int q = 0; q < NE; q++) {
            int nb = (counts[q] + 127) >> 7;
            if (bsw >= s && bsw < s + nb) { e = q; m0 = (bsw - s) << 7; }
            s += nb;
        }
    }
    if (e < 0) return;
    const int cnt = counts[e];
    const int n0 = blockIdx.y * 128;
    __shared__ __align__(16) unsigned short As[3 * ASZ];
    __shared__ __align__(16) unsigned short Bs[3 * BSZ];
    __shared__ int slot_s[128];
    const int tid = threadIdx.x, lane = tid & 63, wid = tid >> 6;
    if (tid < 128) {
        int r = m0 + tid;
        slot_s[tid] = lists[e * NT + (r < cnt ? r : cnt - 1)];
    }
    __syncthreads();

    const int rsub = lane >> 2;
    const int sw = (((lane & 3) ^ ((rsub >> 1) & 3)) * 8);
    const int row0 = wid * 16 + rsub;
    const unsigned short* gA0 = hbuf + (size_t)slot_s[row0] * ID + sw;
    const unsigned short* gA1 = hbuf + (size_t)slot_s[row0 + 64] * ID + sw;
    const unsigned short* gB0 = w2b + ((size_t)e * HD + n0 + row0) * ID + sw;
    const unsigned short* gB1 = gB0 + (size_t)64 * ID;
    auto stage = [&](int bf) {
        gload16(gA0, As + bf * ASZ + wid * 512);       gA0 += BK;
        gload16(gA1, As + bf * ASZ + (wid + 4) * 512); gA1 += BK;
        gload16(gB0, Bs + bf * BSZ + wid * 512);       gB0 += BK;
        gload16(gB1, Bs + bf * BSZ + (wid + 4) * 512); gB1 += BK;
    };

    const int wr = wid >> 1, wc = wid & 1;
    const int l15 = lane & 15, l4 = lane >> 4;
    const int aBase = (wr * 64 + l15) * BK;
    const int bBase = (wc * 64 + l15) * BK;
    const int cs = (l4 ^ ((l15 >> 1) & 3)) * 8;

    f32x4 acc[4][4];
    f32x4 zero = {0.f, 0.f, 0.f, 0.f};
#pragma unroll
    for (int m = 0; m < 4; m++)
#pragma unroll
        for (int n = 0; n < 4; n++) acc[m][n] = zero;

    const int NK = ID / BK;      // 96
    stage(0); stage(1);
    int cur = 0, pf = 2;
    for (int kt = 0; kt < NK; ++kt) {
        if (kt + 1 < NK) asm volatile("s_waitcnt vmcnt(4)\ns_barrier" ::: "memory");
        else             asm volatile("s_waitcnt vmcnt(0)\ns_barrier" ::: "memory");
        if (kt + 2 < NK) { stage(pf); pf = (pf == 2) ? 0 : pf + 1; }
        const unsigned short* Ab = As + cur * ASZ;
        const unsigned short* Bb = Bs + cur * BSZ;
        bf16x8 a[4], b[4];
#pragma unroll
        for (int m = 0; m < 4; m++) a[m] = *(const bf16x8*)(Ab + aBase + m * 512 + cs);
#pragma unroll
        for (int n = 0; n < 4; n++) b[n] = *(const bf16x8*)(Bb + bBase + n * 512 + cs);
#pragma unroll
        for (int m = 0; m < 4; m++)
#pragma unroll
            for (int n = 0; n < 4; n++)
                acc[m][n] = __builtin_amdgcn_mfma_f32_16x16x32_bf16(b[n], a[m], acc[m][n], 0, 0, 0);
        cur = (cur == 2) ? 0 : cur + 1;
    }
    const int rj = l4 * 4;
#pragma unroll
    for (int m = 0; m < 4; m++) {
        int lr2 = wr * 64 + m * 16 + l15;
        if (m0 + lr2 < cnt) {
            int slot = slot_s[lr2];
            float g = gates[slot];
            unsigned short* pp = pout + (size_t)slot * HD + n0 + wc * 64 + rj;
#pragma unroll
            for (int n = 0; n < 4; n++) {
                uint2 pk;
                pk.x = cvt_pk_bf16(g * acc[m][n][0], g * acc[m][n][1]);
                pk.y = cvt_pk_bf16(g * acc[m][n][2], g * acc[m][n][3]);
                *(uint2*)(pp + n * 16) = pk;
            }
        }
    }
}

// out[t] = pout[2t] + pout[2t+1] + bias   (pout is bf16)
__global__ void k_combine(const unsigned short* __restrict__ pout, const float* __restrict__ bias,
                          float4* __restrict__ out) {
    int idx = blockIdx.x * 256 + threadIdx.x;   // over NT*HD/4
    int t = idx / (HD / 4);
    int c = idx - t * (HD / 4);
    ushort4 a = ((const ushort4*)pout)[(size_t)t * (2 * HD / 4) + c];
    ushort4 b = ((const ushort4*)pout)[(size_t)t * (2 * HD / 4) + HD / 4 + c];
    float4 bb = ((const float4*)bias)[c];
    float4 r;
    r.x = bf2f(a.x) + bf2f(b.x) + bb.x;
    r.y = bf2f(a.y) + bf2f(b.y) + bb.y;
    r.z = bf2f(a.z) + bf2f(b.z) + bb.z;
    r.w = bf2f(a.w) + bf2f(b.w) + bb.w;
    out[idx] = r;
}

extern "C" void kernel_launch(void* const* d_in, const int* in_sizes, int n_in,
                              void* d_out, int out_size, void* d_ws, size_t ws_size,
                              hipStream_t stream) {
    const float* x    = (const float*)d_in[0];
    const float* rw   = (const float*)d_in[1];
    const float* w1   = (const float*)d_in[2];
    const float* w2   = (const float*)d_in[3];
    const float* bias = (const float*)d_in[4];
    float* out = (float*)d_out;

    char* ws = (char*)d_ws;
    size_t off = 0;
    auto alloc = [&](size_t bytes) -> char* {
        char* p = ws + off;
        off += (bytes + 255) & ~(size_t)255;
        return p;
    };
    int*            counts = (int*)alloc(NE * 4);
    int*            lists  = (int*)alloc((size_t)NE * NT * 4);
    float*          gates  = (float*)alloc((size_t)NT * 2 * 4);
    uchar2*         choice = (uchar2*)alloc((size_t)NT * 2);
    unsigned short* xb     = (unsigned short*)alloc((size_t)NT * HD * 2);
    unsigned short* w1b    = (unsigned short*)alloc((size_t)NE * ID * HD * 2);
    unsigned short* w2b    = (unsigned short*)alloc((size_t)NE * HD * ID * 2);
    unsigned short* hbuf   = (unsigned short*)alloc((size_t)NT * 2 * ID * 2);
    unsigned short* pout   = (unsigned short*)alloc((size_t)NT * 2 * HD * 2);

    k_front<<<dim3(RT_BLOCKS + CONV_BLOCKS), dim3(256), 0, stream>>>(
        x, rw, (const float4*)w1, (const float4*)w2,
        (ushort4*)w1b, (ushort4*)w2b, (ushort4*)xb, gates, choice);
    k_scatter<<<dim3(NE), dim3(256), 0, stream>>>(choice, lists, counts);
    k_gemm1<<<dim3(MAXB, ID / 128), dim3(256), 0, stream>>>(xb, w1b, lists, counts, hbuf);
    k_gemm2<<<dim3(MAXB, HD / 128), dim3(256), 0, stream>>>(hbuf, w2b, lists, counts, gates, pout);
    k_combine<<<dim3(NT * HD / 4 / 256), dim3(256), 0, stream>>>(pout, bias, (float4*)out);
}

// Round 11
// 279.348 us; speedup vs baseline: 1.1480x; 1.1480x over previous
//
#include <hip/hip_runtime.h>
#include <hip/hip_bf16.h>
#include <math.h>

#define NT 8192
#define HD 768
#define ID 3072
#define NE 8
#define BK 32
#define MAXB 72     // >= sum_e ceil(cnt_e/256); 72 = 8*9 (bijective XCD swizzle)
#define ASZ (256 * BK)
#define BSZ (128 * BK)
#define RT_BLOCKS 256                         // router blocks (32 tokens each)
#define CW1_BLOCKS (NE * ID * HD / 4 / 1024)  // 4608: w1 convert, 4 float4/thread @256
#define G1_GEMM (MAXB * (ID / 128))           // 1728 gemm blocks in k_gemm1
#define CW2_BLOCKS (NE * HD * ID / 4 / 2048)  // 2304: w2 convert, 4 float4/thread @512

typedef __bf16 bf16x8 __attribute__((ext_vector_type(8)));
typedef float f32x4 __attribute__((ext_vector_type(4)));

__device__ __forceinline__ unsigned short f2bf(float f) {
    union { float f; unsigned u; } v; v.f = f;
    unsigned r = v.u + 0x7FFFu + ((v.u >> 16) & 1u);   // RNE
    return (unsigned short)(r >> 16);
}
__device__ __forceinline__ float bf2f(unsigned short b) {
    union { unsigned u; float f; } v; v.u = ((unsigned)b) << 16;
    return v.f;
}
// packed RNE f32x2 -> bf16x2 (single instruction)
__device__ __forceinline__ unsigned cvt_pk_bf16(float lo, float hi) {
    unsigned r;
    asm("v_cvt_pk_bf16_f32 %0, %1, %2" : "=v"(r) : "v"(lo), "v"(hi));
    return r;
}
// gelu(tanh form) == v * sigmoid(2u). 1 exp + 1 rcp.
__device__ __forceinline__ float gelu_s(float v) {
    float z = v * (1.5957691216057308f + 0.07135481283687945f * v * v);
    float e = __expf(-z);
    return v * __builtin_amdgcn_rcpf(1.0f + e);
}

// global->LDS direct copy, 16B/lane. LDS dest = wave-uniform base + lane*16.
__device__ __forceinline__ void gload16(const void* g, void* l) {
    auto* lds = reinterpret_cast<__attribute__((address_space(3))) unsigned int*>(
        reinterpret_cast<uintptr_t>(l));
    auto* gp = reinterpret_cast<const __attribute__((address_space(1))) unsigned int*>(
        reinterpret_cast<uintptr_t>(g));
    __builtin_amdgcn_global_load_lds(gp, lds, 16, 0, 0);
}

// expert/m0 decode from counts for 256-row m-tiles (both GEMMs).
__device__ __forceinline__ void decode_em(const int* counts, int bsw, int& e, int& m0) {
    e = -1; m0 = 0;
    int s = 0;
#pragma unroll
    for (int q = 0; q < NE; q++) {
        int nb = (counts[q] + 255) >> 8;
        if (bsw >= s && bsw < s + nb) { e = q; m0 = (bsw - s) << 8; }
        s += nb;
    }
}

// Fused front: blocks [0,RT_BLOCKS) = router; rest = w1 fp32->bf16 convert.
__global__ void k_front(const float* __restrict__ x, const float* __restrict__ rw,
                        const float4* __restrict__ w1, ushort4* __restrict__ w1b,
                        ushort4* __restrict__ xb4, float* __restrict__ gates,
                        uchar2* __restrict__ choice) {
    __shared__ float rws[NE * HD];
    const int tid = threadIdx.x;
    if (blockIdx.x >= RT_BLOCKS) {
        int base = (blockIdx.x - RT_BLOCKS) * 1024 + tid;
#pragma unroll
        for (int i = 0; i < 4; i++) {
            int idx = base + i * 256;
            float4 a = w1[idx];
            ushort4 ra;
            ra.x = f2bf(a.x); ra.y = f2bf(a.y); ra.z = f2bf(a.z); ra.w = f2bf(a.w);
            w1b[idx] = ra;
        }
        return;
    }
    for (int i = tid; i < NE * HD / 4; i += 256)
        ((float4*)rws)[i] = ((const float4*)rw)[i];
    __syncthreads();
    const int wid = tid >> 6, lane = tid & 63;
    const float4* rws4 = (const float4*)rws;
    for (int it = 0; it < 8; ++it) {
        const int t = blockIdx.x * 32 + wid * 8 + it;
        const float4* xp4 = (const float4*)(x + (size_t)t * HD);
        float acc[NE];
#pragma unroll
        for (int e = 0; e < NE; e++) acc[e] = 0.f;
#pragma unroll
        for (int j = 0; j < HD / 256; j++) {
            float4 v = xp4[lane + 64 * j];
            ushort4 o;
            o.x = f2bf(v.x); o.y = f2bf(v.y); o.z = f2bf(v.z); o.w = f2bf(v.w);
            xb4[(size_t)t * (HD / 4) + lane + 64 * j] = o;
#pragma unroll
            for (int e = 0; e < NE; e++) {
                float4 w = rws4[e * (HD / 4) + lane + 64 * j];
                acc[e] += v.x * w.x + v.y * w.y + v.z * w.z + v.w * w.w;
            }
        }
#pragma unroll
        for (int e = 0; e < NE; e++)
            for (int off = 32; off; off >>= 1) acc[e] += __shfl_xor(acc[e], off);
        if (lane == 0) {
            float mx = acc[0];
#pragma unroll
            for (int e = 1; e < NE; e++) mx = fmaxf(mx, acc[e]);
            float p[NE], s = 0.f;
#pragma unroll
            for (int e = 0; e < NE; e++) { p[e] = __expf(acc[e] - mx); s += p[e]; }
            float inv = 1.f / s;
            int i1 = 0; float b1 = p[0];
#pragma unroll
            for (int e = 1; e < NE; e++) if (p[e] > b1) { b1 = p[e]; i1 = e; }
            int i2 = (i1 == 0) ? 1 : 0; float b2 = p[i2];
#pragma unroll
            for (int e = 0; e < NE; e++) if (e != i1 && p[e] > b2) { b2 = p[e]; i2 = e; }
            choice[t].x = (unsigned char)i1;
            choice[t].y = (unsigned char)i2;
            gates[2 * t] = b1 * inv;
            gates[2 * t + 1] = b2 * inv;
        }
    }
}

// Router phase 2: one block per expert; ballot/prefix-scan compaction. No atomics.
__global__ void k_scatter(const uchar2* __restrict__ choice,
                          int* __restrict__ lists, int* __restrict__ counts) {
    const int e = blockIdx.x;
    const int tid = threadIdx.x, wid = tid >> 6, lane = tid & 63;
    __shared__ int wtot[4];
    __shared__ int running;
    if (tid == 0) running = 0;
    __syncthreads();
    for (int t0 = 0; t0 < NT; t0 += 256) {
        const int t = t0 + tid;
        uchar2 c = choice[t];
        bool m1 = (c.x == e), m2 = (c.y == e);
        bool m = m1 || m2;
        int slot = m1 ? 2 * t : 2 * t + 1;
        unsigned long long mask = __ballot(m);
        int off = __popcll(mask & ((1ULL << lane) - 1ULL));
        if (lane == 0) wtot[wid] = __popcll(mask);
        __syncthreads();
        int base = running;
        for (int w = 0; w < wid; w++) base += wtot[w];
        if (m) lists[e * NT + base + off] = slot;
        __syncthreads();
        if (tid == 0) running += wtot[0] + wtot[1] + wtot[2] + wtot[3];
        __syncthreads();
    }
    if (tid == 0) counts[e] = running;
}

// Both GEMMs: 256x128 tile, 8 waves (4M x 2N, wave tile 64x64), BK=32,
// 3 LDS buffers (73 KB), depth-2 counted-vmcnt pipeline (3 gload16/wave/stage,
// wait vmcnt(3)). LDS rows 64 B; 16B-chunk c of row r stored at c ^ ((r>>1)&3):
// ds_read_b128 2-way (free); staging coalesced via pre-permuted global source.
// MFMA operand swap (b,a) -> D^T fragments -> packed uint2 stores (cvt_pk).
// XCD swizzle bijective (72 = 8*9 m-entries).

// GEMM1 + fused w2 convert. Blocks [0,G1_GEMM): GEMM (flattened m,n); blocks
// [G1_GEMM, G1_GEMM+CW2_BLOCKS): w2 fp32->bf16 (backfills tail; gemm2 sees
// complete w2b at the kernel boundary).
__launch_bounds__(512, 2)
__global__ void k_gemm1(const unsigned short* __restrict__ xb, const unsigned short* __restrict__ w1b,
                        const float4* __restrict__ w2, ushort4* __restrict__ w2b,
                        const int* __restrict__ lists, const int* __restrict__ counts,
                        unsigned short* __restrict__ hbuf) {
    const int tid = threadIdx.x;
    if (blockIdx.x >= G1_GEMM) {
        int base = (blockIdx.x - G1_GEMM) * 2048 + tid;
#pragma unroll
        for (int i = 0; i < 4; i++) {
            int idx = base + i * 512;
            float4 a = w2[idx];
            ushort4 ra;
            ra.x = f2bf(a.x); ra.y = f2bf(a.y); ra.z = f2bf(a.z); ra.w = f2bf(a.w);
            w2b[idx] = ra;
        }
        return;
    }
    const int mi = blockIdx.x % MAXB;
    const int ny = blockIdx.x / MAXB;
    const int bsw = (mi & 7) * (MAXB >> 3) + (mi >> 3);
    int e, m0;
    decode_em(counts, bsw, e, m0);
    if (e < 0) return;
    const int cnt = counts[e];
    const int n0 = ny * 128;
    __shared__ __align__(16) unsigned short As[3 * ASZ];
    __shared__ __align__(16) unsigned short Bs[3 * BSZ];
    __shared__ int slot_s[256];
    const int lane = tid & 63, wid = tid >> 6;
    if (tid < 256) {
        int r = m0 + tid;
        slot_s[tid] = lists[e * NT + (r < cnt ? r : cnt - 1)];
    }
    __syncthreads();

    const int rsub = lane >> 2;
    const int sw = (((lane & 3) ^ ((rsub >> 1) & 3)) * 8);
    const int row0 = wid * 16 + rsub;
    const unsigned short* gA0 = xb + (size_t)(slot_s[row0] >> 1) * HD + sw;
    const unsigned short* gA1 = xb + (size_t)(slot_s[row0 + 128] >> 1) * HD + sw;
    const unsigned short* gB0 = w1b + ((size_t)e * ID + n0 + row0) * HD + sw;
    auto stage = [&](int bf) {
        gload16(gA0, As + bf * ASZ + wid * 512);       gA0 += BK;
        gload16(gA1, As + bf * ASZ + (wid + 8) * 512); gA1 += BK;
        gload16(gB0, Bs + bf * BSZ + wid * 512);       gB0 += BK;
    };

    const int wr = wid >> 1, wc = wid & 1;
    const int l15 = lane & 15, l4 = lane >> 4;
    const int aBase = (wr * 64 + l15) * BK;
    const int bBase = (wc * 64 + l15) * BK;
    const int cs = (l4 ^ ((l15 >> 1) & 3)) * 8;

    f32x4 acc[4][4];
    f32x4 zero = {0.f, 0.f, 0.f, 0.f};
#pragma unroll
    for (int m = 0; m < 4; m++)
#pragma unroll
        for (int n = 0; n < 4; n++) acc[m][n] = zero;

    const int NK = HD / BK;      // 24
    stage(0); stage(1);
    int cur = 0, pf = 2;
    for (int kt = 0; kt < NK; ++kt) {
        if (kt + 1 < NK) asm volatile("s_waitcnt vmcnt(3)\ns_barrier" ::: "memory");
        else             asm volatile("s_waitcnt vmcnt(0)\ns_barrier" ::: "memory");
        if (kt + 2 < NK) { stage(pf); pf = (pf == 2) ? 0 : pf + 1; }
        const unsigned short* Ab = As + cur * ASZ;
        const unsigned short* Bb = Bs + cur * BSZ;
        bf16x8 a[4], b[4];
#pragma unroll
        for (int m = 0; m < 4; m++) a[m] = *(const bf16x8*)(Ab + aBase + m * 512 + cs);
#pragma unroll
        for (int n = 0; n < 4; n++) b[n] = *(const bf16x8*)(Bb + bBase + n * 512 + cs);
#pragma unroll
        for (int m = 0; m < 4; m++)
#pragma unroll
            for (int n = 0; n < 4; n++)
                acc[m][n] = __builtin_amdgcn_mfma_f32_16x16x32_bf16(b[n], a[m], acc[m][n], 0, 0, 0);
        cur = (cur == 2) ? 0 : cur + 1;
    }
    const int rj = l4 * 4;
#pragma unroll
    for (int m = 0; m < 4; m++) {
        int lr2 = wr * 64 + m * 16 + l15;
        if (m0 + lr2 < cnt) {
            int slot = slot_s[lr2];
            unsigned short* hp = hbuf + (size_t)slot * ID + n0 + wc * 64 + rj;
#pragma unroll
            for (int n = 0; n < 4; n++) {
                uint2 pk;
                pk.x = cvt_pk_bf16(gelu_s(acc[m][n][0]), gelu_s(acc[m][n][1]));
                pk.y = cvt_pk_bf16(gelu_s(acc[m][n][2]), gelu_s(acc[m][n][3]));
                *(uint2*)(hp + n * 16) = pk;
            }
        }
    }
}

// GEMM2: pout[slot] = gate[slot] * (h_gathered @ w2[e]^T). K=3072, NK=96.
__launch_bounds__(512, 2)
__global__ void k_gemm2(const unsigned short* __restrict__ hbuf, const unsigned short* __restrict__ w2b,
                        const int* __restrict__ lists, const int* __restrict__ counts,
                        const float* __restrict__ gates, unsigned short* __restrict__ pout) {
    const int bsw = (blockIdx.x & 7) * (MAXB >> 3) + (blockIdx.x >> 3);
    int e, m0;
    decode_em(counts, bsw, e, m0);
    if (e < 0) return;
    const int cnt = counts[e];
    const int n0 = blockIdx.y * 128;
    __shared__ __align__(16) unsigned short As[3 * ASZ];
    __shared__ __align__(16) unsigned short Bs[3 * BSZ];
    __shared__ int slot_s[256];
    const int tid = threadIdx.x, lane = tid & 63, wid = tid >> 6;
    if (tid < 256) {
        int r = m0 + tid;
        slot_s[tid] = lists[e * NT + (r < cnt ? r : cnt - 1)];
    }
    __syncthreads();

    const int rsub = lane >> 2;
    const int sw = (((lane & 3) ^ ((rsub >> 1) & 3)) * 8);
    const int row0 = wid * 16 + rsub;
    const unsigned short* gA0 = hbuf + (size_t)slot_s[row0] * ID + sw;
    const unsigned short* gA1 = hbuf + (size_t)slot_s[row0 + 128] * ID + sw;
    const unsigned short* gB0 = w2b + ((size_t)e * HD + n0 + row0) * ID + sw;
    auto stage = [&](int bf) {
        gload16(gA0, As + bf * ASZ + wid * 512);       gA0 += BK;
        gload16(gA1, As + bf * ASZ + (wid + 8) * 512); gA1 += BK;
        gload16(gB0, Bs + bf * BSZ + wid * 512);       gB0 += BK;
    };

    const int wr = wid >> 1, wc = wid & 1;
    const int l15 = lane & 15, l4 = lane >> 4;
    const int aBase = (wr * 64 + l15) * BK;
    const int bBase = (wc * 64 + l15) * BK;
    const int cs = (l4 ^ ((l15 >> 1) & 3)) * 8;

    f32x4 acc[4][4];
    f32x4 zero = {0.f, 0.f, 0.f, 0.f};
#pragma unroll
    for (int m = 0; m < 4; m++)
#pragma unroll
        for (int n = 0; n < 4; n++) acc[m][n] = zero;

    const int NK = ID / BK;      // 96
    stage(0); stage(1);
    int cur = 0, pf = 2;
    for (int kt = 0; kt < NK; ++kt) {
        if (kt + 1 < NK) asm volatile("s_waitcnt vmcnt(3)\ns_barrier" ::: "memory");
        else             asm volatile("s_waitcnt vmcnt(0)\ns_barrier" ::: "memory");
        if (kt + 2 < NK) { stage(pf); pf = (pf == 2) ? 0 : pf + 1; }
        const unsigned short* Ab = As + cur * ASZ;
        const unsigned short* Bb = Bs + cur * BSZ;
        bf16x8 a[4], b[4];
#pragma unroll
        for (int m = 0; m < 4; m++) a[m] = *(const bf16x8*)(Ab + aBase + m * 512 + cs);
#pragma unroll
        for (int n = 0; n < 4; n++) b[n] = *(const bf16x8*)(Bb + bBase + n * 512 + cs);
#pragma unroll
        for (int m = 0; m < 4; m++)
#pragma unroll
            for (int n = 0; n < 4; n++)
                acc[m][n] = __builtin_amdgcn_mfma_f32_16x16x32_bf16(b[n], a[m], acc[m][n], 0, 0, 0);
        cur = (cur == 2) ? 0 : cur + 1;
    }
    const int rj = l4 * 4;
#pragma unroll
    for (int m = 0; m < 4; m++) {
        int lr2 = wr * 64 + m * 16 + l15;
        if (m0 + lr2 < cnt) {
            int slot = slot_s[lr2];
            float g = gates[slot];
            unsigned short* pp = pout + (size_t)slot * HD + n0 + wc * 64 + rj;
#pragma unroll
            for (int n = 0; n < 4; n++) {
                uint2 pk;
                pk.x = cvt_pk_bf16(g * acc[m][n][0], g * acc[m][n][1]);
                pk.y = cvt_pk_bf16(g * acc[m][n][2], g * acc[m][n][3]);
                *(uint2*)(pp + n * 16) = pk;
            }
        }
    }
}

// out[t] = pout[2t] + pout[2t+1] + bias   (pout is bf16)
__global__ void k_combine(const unsigned short* __restrict__ pout, const float* __restrict__ bias,
                          float4* __restrict__ out) {
    int idx = blockIdx.x * 256 + threadIdx.x;   // over NT*HD/4
    int t = idx / (HD / 4);
    int c = idx - t * (HD / 4);
    ushort4 a = ((const ushort4*)pout)[(size_t)t * (2 * HD / 4) + c];
    ushort4 b = ((const ushort4*)pout)[(size_t)t * (2 * HD / 4) + HD / 4 + c];
    float4 bb = ((const float4*)bias)[c];
    float4 r;
    r.x = bf2f(a.x) + bf2f(b.x) + bb.x;
    r.y = bf2f(a.y) + bf2f(b.y) + bb.y;
    r.z = bf2f(a.z) + bf2f(b.z) + bb.z;
    r.w = bf2f(a.w) + bf2f(b.w) + bb.w;
    out[idx] = r;
}

extern "C" void kernel_launch(void* const* d_in, const int* in_sizes, int n_in,
                              void* d_out, int out_size, void* d_ws, size_t ws_size,
                              hipStream_t stream) {
    const float* x    = (const float*)d_in[0];
    const float* rw   = (const float*)d_in[1];
    const float* w1   = (const float*)d_in[2];
    const float* w2   = (const float*)d_in[3];
    const float* bias = (const float*)d_in[4];
    float* out = (float*)d_out;

    char* ws = (char*)d_ws;
    size_t off = 0;
    auto alloc = [&](size_t bytes) -> char* {
        char* p = ws + off;
        off += (bytes + 255) & ~(size_t)255;
        return p;
    };
    int*            counts = (int*)alloc(NE * 4);
    int*            lists  = (int*)alloc((size_t)NE * NT * 4);
    float*          gates  = (float*)alloc((size_t)NT * 2 * 4);
    uchar2*         choice = (uchar2*)alloc((size_t)NT * 2);
    unsigned short* xb     = (unsigned short*)alloc((size_t)NT * HD * 2);
    unsigned short* w1b    = (unsigned short*)alloc((size_t)NE * ID * HD * 2);
    unsigned short* w2b    = (unsigned short*)alloc((size_t)NE * HD * ID * 2);
    unsigned short* hbuf   = (unsigned short*)alloc((size_t)NT * 2 * ID * 2);
    unsigned short* pout   = (unsigned short*)alloc((size_t)NT * 2 * HD * 2);

    k_front<<<dim3(RT_BLOCKS + CW1_BLOCKS), dim3(256), 0, stream>>>(
        x, rw, (const float4*)w1, (ushort4*)w1b, (ushort4*)xb, gates, choice);
    k_scatter<<<dim3(NE), dim3(256), 0, stream>>>(choice, lists, counts);
    k_gemm1<<<dim3(G1_GEMM + CW2_BLOCKS), dim3(512), 0, stream>>>(
        xb, w1b, (const float4*)w2, (ushort4*)w2b, lists, counts, hbuf);
    k_gemm2<<<dim3(MAXB, HD / 128), dim3(512), 0, stream>>>(hbuf, w2b, lists, counts, gates, pout);
    k_combine<<<dim3(NT * HD / 4 / 256), dim3(256), 0, stream>>>(pout, bias, (float4*)out);
}

// Round 12
// 262.652 us; speedup vs baseline: 1.2210x; 1.0636x over previous
//
#include <hip/hip_runtime.h>
#include <hip/hip_bf16.h>
#include <math.h>

#define NT 8192
#define HD 768
#define ID 3072
#define NE 8
#define BK 32
#define MAXB 72     // >= sum_e ceil(cnt_e/256); 72 = 8*9 (bijective XCD swizzle)
#define ASZ (256 * BK)
#define BSZ (128 * BK)
#define RT_BLOCKS 256                         // router blocks (32 tokens each)
#define CW1_BLOCKS (NE * ID * HD / 4 / 1024)  // 4608: w1 convert, 4 float4/thread @256
#define G1_GEMM (MAXB * (ID / 128))           // 1728 gemm blocks in k_gemm1
#define CW2_BLOCKS (NE * HD * ID / 4 / 2048)  // 2304: w2 convert, 4 float4/thread @512

typedef __bf16 bf16x8 __attribute__((ext_vector_type(8)));
typedef float f32x4 __attribute__((ext_vector_type(4)));

__device__ __forceinline__ unsigned short f2bf(float f) {
    union { float f; unsigned u; } v; v.f = f;
    unsigned r = v.u + 0x7FFFu + ((v.u >> 16) & 1u);   // RNE
    return (unsigned short)(r >> 16);
}
__device__ __forceinline__ float bf2f(unsigned short b) {
    union { unsigned u; float f; } v; v.u = ((unsigned)b) << 16;
    return v.f;
}
// packed RNE f32x2 -> bf16x2 (single instruction)
__device__ __forceinline__ unsigned cvt_pk_bf16(float lo, float hi) {
    unsigned r;
    asm("v_cvt_pk_bf16_f32 %0, %1, %2" : "=v"(r) : "v"(lo), "v"(hi));
    return r;
}
// gelu(tanh form) == v * sigmoid(2u). 1 exp + 1 rcp.
__device__ __forceinline__ float gelu_s(float v) {
    float z = v * (1.5957691216057308f + 0.07135481283687945f * v * v);
    float e = __expf(-z);
    return v * __builtin_amdgcn_rcpf(1.0f + e);
}

// global->LDS direct copy, 16B/lane. LDS dest = wave-uniform base + lane*16.
__device__ __forceinline__ void gload16(const void* g, void* l) {
    auto* lds = reinterpret_cast<__attribute__((address_space(3))) unsigned int*>(
        reinterpret_cast<uintptr_t>(l));
    auto* gp = reinterpret_cast<const __attribute__((address_space(1))) unsigned int*>(
        reinterpret_cast<uintptr_t>(g));
    __builtin_amdgcn_global_load_lds(gp, lds, 16, 0, 0);
}

// expert/m0 decode from counts for 256-row m-tiles (both GEMMs).
__device__ __forceinline__ void decode_em(const int* counts, int bsw, int& e, int& m0) {
    e = -1; m0 = 0;
    int s = 0;
#pragma unroll
    for (int q = 0; q < NE; q++) {
        int nb = (counts[q] + 255) >> 8;
        if (bsw >= s && bsw < s + nb) { e = q; m0 = (bsw - s) << 8; }
        s += nb;
    }
}

// Fused front: blocks [0,RT_BLOCKS) = router; rest = w1 fp32->bf16 convert.
__global__ void k_front(const float* __restrict__ x, const float* __restrict__ rw,
                        const float4* __restrict__ w1, ushort4* __restrict__ w1b,
                        ushort4* __restrict__ xb4, float* __restrict__ gates,
                        uchar2* __restrict__ choice) {
    __shared__ float rws[NE * HD];
    const int tid = threadIdx.x;
    if (blockIdx.x >= RT_BLOCKS) {
        int base = (blockIdx.x - RT_BLOCKS) * 1024 + tid;
#pragma unroll
        for (int i = 0; i < 4; i++) {
            int idx = base + i * 256;
            float4 a = w1[idx];
            ushort4 ra;
            ra.x = f2bf(a.x); ra.y = f2bf(a.y); ra.z = f2bf(a.z); ra.w = f2bf(a.w);
            w1b[idx] = ra;
        }
        return;
    }
    for (int i = tid; i < NE * HD / 4; i += 256)
        ((float4*)rws)[i] = ((const float4*)rw)[i];
    __syncthreads();
    const int wid = tid >> 6, lane = tid & 63;
    const float4* rws4 = (const float4*)rws;
    for (int it = 0; it < 8; ++it) {
        const int t = blockIdx.x * 32 + wid * 8 + it;
        const float4* xp4 = (const float4*)(x + (size_t)t * HD);
        float acc[NE];
#pragma unroll
        for (int e = 0; e < NE; e++) acc[e] = 0.f;
#pragma unroll
        for (int j = 0; j < HD / 256; j++) {
            float4 v = xp4[lane + 64 * j];
            ushort4 o;
            o.x = f2bf(v.x); o.y = f2bf(v.y); o.z = f2bf(v.z); o.w = f2bf(v.w);
            xb4[(size_t)t * (HD / 4) + lane + 64 * j] = o;
#pragma unroll
            for (int e = 0; e < NE; e++) {
                float4 w = rws4[e * (HD / 4) + lane + 64 * j];
                acc[e] += v.x * w.x + v.y * w.y + v.z * w.z + v.w * w.w;
            }
        }
#pragma unroll
        for (int e = 0; e < NE; e++)
            for (int off = 32; off; off >>= 1) acc[e] += __shfl_xor(acc[e], off);
        if (lane == 0) {
            float mx = acc[0];
#pragma unroll
            for (int e = 1; e < NE; e++) mx = fmaxf(mx, acc[e]);
            float p[NE], s = 0.f;
#pragma unroll
            for (int e = 0; e < NE; e++) { p[e] = __expf(acc[e] - mx); s += p[e]; }
            float inv = 1.f / s;
            int i1 = 0; float b1 = p[0];
#pragma unroll
            for (int e = 1; e < NE; e++) if (p[e] > b1) { b1 = p[e]; i1 = e; }
            int i2 = (i1 == 0) ? 1 : 0; float b2 = p[i2];
#pragma unroll
            for (int e = 0; e < NE; e++) if (e != i1 && p[e] > b2) { b2 = p[e]; i2 = e; }
            choice[t].x = (unsigned char)i1;
            choice[t].y = (unsigned char)i2;
            gates[2 * t] = b1 * inv;
            gates[2 * t + 1] = b2 * inv;
        }
    }
}

// Scatter phase A: 64 blocks = (expert e = bx>>3, chunk c = bx&7, 1024 tokens).
// Ballot-count matches -> ccnt[e*8+c]. No atomics.
__global__ void k_cnt(const uchar2* __restrict__ choice, int* __restrict__ ccnt) {
    const int e = blockIdx.x >> 3, c = blockIdx.x & 7;
    const int tid = threadIdx.x, wid = tid >> 6, lane = tid & 63;
    __shared__ int ws[4];
    int tot = 0;
#pragma unroll
    for (int p = 0; p < 4; p++) {
        int t = c * 1024 + p * 256 + tid;
        uchar2 ch = choice[t];
        bool m = (ch.x == e) || (ch.y == e);
        unsigned long long mask = __ballot(m);
        if (lane == 0) tot += __popcll(mask);
    }
    if (lane == 0) ws[wid] = tot;
    __syncthreads();
    if (tid == 0) ccnt[blockIdx.x] = ws[0] + ws[1] + ws[2] + ws[3];
}

// Scatter phase B: same 64-block mapping; base = prefix of ccnt[e][<c]; 4 ballot
// scan passes write the slot list. Block (e,7) also writes counts[e].
__global__ void k_wr(const uchar2* __restrict__ choice, const int* __restrict__ ccnt,
                     int* __restrict__ lists, int* __restrict__ counts) {
    const int e = blockIdx.x >> 3, c = blockIdx.x & 7;
    const int tid = threadIdx.x, wid = tid >> 6, lane = tid & 63;
    __shared__ int wtot[4];
    __shared__ int running;
    if (tid == 0) {
        int b = 0;
        for (int q = 0; q < c; q++) b += ccnt[e * 8 + q];
        running = b;
        if (c == 7) counts[e] = b + ccnt[e * 8 + 7];
    }
    __syncthreads();
#pragma unroll
    for (int p = 0; p < 4; p++) {
        int t = c * 1024 + p * 256 + tid;
        uchar2 ch = choice[t];
        bool m1 = (ch.x == e), m2 = (ch.y == e);
        bool m = m1 || m2;
        int slot = m1 ? 2 * t : 2 * t + 1;
        unsigned long long mask = __ballot(m);
        int off = __popcll(mask & ((1ULL << lane) - 1ULL));
        if (lane == 0) wtot[wid] = __popcll(mask);
        __syncthreads();
        int base = running;
        for (int w = 0; w < wid; w++) base += wtot[w];
        if (m) lists[e * NT + base + off] = slot;
        __syncthreads();
        if (tid == 0) running += wtot[0] + wtot[1] + wtot[2] + wtot[3];
        __syncthreads();
    }
}

// Both GEMMs: 256x128 tile, 8 waves (4M x 2N, wave tile 64x64), BK=32,
// 3 LDS buffers (73 KB), depth-2 counted-vmcnt pipeline (3 gload16/wave/stage,
// wait vmcnt(3)). LDS rows 64 B; 16B-chunk c of row r stored at c ^ ((r>>1)&3):
// ds_read_b128 2-way (free); staging coalesced via pre-permuted global source.
// MFMA operand swap (b,a) -> D^T fragments -> packed uint2 stores (cvt_pk).
// s_setprio(1) around the MFMA cluster. XCD swizzle bijective (72 = 8*9).

// GEMM1 + fused w2 convert. Blocks [0,G1_GEMM): GEMM; rest: w2 fp32->bf16
// (backfills the GEMM tail; gemm2 sees complete w2b at the kernel boundary).
__launch_bounds__(512, 2)
__global__ void k_gemm1(const unsigned short* __restrict__ xb, const unsigned short* __restrict__ w1b,
                        const float4* __restrict__ w2, ushort4* __restrict__ w2b,
                        const int* __restrict__ lists, const int* __restrict__ counts,
                        unsigned short* __restrict__ hbuf) {
    const int tid = threadIdx.x;
    if (blockIdx.x >= G1_GEMM) {
        int base = (blockIdx.x - G1_GEMM) * 2048 + tid;
#pragma unroll
        for (int i = 0; i < 4; i++) {
            int idx = base + i * 512;
            float4 a = w2[idx];
            ushort4 ra;
            ra.x = f2bf(a.x); ra.y = f2bf(a.y); ra.z = f2bf(a.z); ra.w = f2bf(a.w);
            w2b[idx] = ra;
        }
        return;
    }
    const int mi = blockIdx.x % MAXB;
    const int ny = blockIdx.x / MAXB;
    const int bsw = (mi & 7) * (MAXB >> 3) + (mi >> 3);
    int e, m0;
    decode_em(counts, bsw, e, m0);
    if (e < 0) return;
    const int cnt = counts[e];
    const int n0 = ny * 128;
    __shared__ __align__(16) unsigned short As[3 * ASZ];
    __shared__ __align__(16) unsigned short Bs[3 * BSZ];
    __shared__ int slot_s[256];
    const int lane = tid & 63, wid = tid >> 6;
    if (tid < 256) {
        int r = m0 + tid;
        slot_s[tid] = lists[e * NT + (r < cnt ? r : cnt - 1)];
    }
    __syncthreads();

    const int rsub = lane >> 2;
    const int sw = (((lane & 3) ^ ((rsub >> 1) & 3)) * 8);
    const int row0 = wid * 16 + rsub;
    const unsigned short* gA0 = xb + (size_t)(slot_s[row0] >> 1) * HD + sw;
    const unsigned short* gA1 = xb + (size_t)(slot_s[row0 + 128] >> 1) * HD + sw;
    const unsigned short* gB0 = w1b + ((size_t)e * ID + n0 + row0) * HD + sw;
    auto stage = [&](int bf) {
        gload16(gA0, As + bf * ASZ + wid * 512);       gA0 += BK;
        gload16(gA1, As + bf * ASZ + (wid + 8) * 512); gA1 += BK;
        gload16(gB0, Bs + bf * BSZ + wid * 512);       gB0 += BK;
    };

    const int wr = wid >> 1, wc = wid & 1;
    const int l15 = lane & 15, l4 = lane >> 4;
    const int aBase = (wr * 64 + l15) * BK;
    const int bBase = (wc * 64 + l15) * BK;
    const int cs = (l4 ^ ((l15 >> 1) & 3)) * 8;

    f32x4 acc[4][4];
    f32x4 zero = {0.f, 0.f, 0.f, 0.f};
#pragma unroll
    for (int m = 0; m < 4; m++)
#pragma unroll
        for (int n = 0; n < 4; n++) acc[m][n] = zero;

    const int NK = HD / BK;      // 24
    stage(0); stage(1);
    int cur = 0, pf = 2;
    for (int kt = 0; kt < NK; ++kt) {
        if (kt + 1 < NK) asm volatile("s_waitcnt vmcnt(3)\ns_barrier" ::: "memory");
        else             asm volatile("s_waitcnt vmcnt(0)\ns_barrier" ::: "memory");
        if (kt + 2 < NK) { stage(pf); pf = (pf == 2) ? 0 : pf + 1; }
        const unsigned short* Ab = As + cur * ASZ;
        const unsigned short* Bb = Bs + cur * BSZ;
        bf16x8 a[4], b[4];
#pragma unroll
        for (int m = 0; m < 4; m++) a[m] = *(const bf16x8*)(Ab + aBase + m * 512 + cs);
#pragma unroll
        for (int n = 0; n < 4; n++) b[n] = *(const bf16x8*)(Bb + bBase + n * 512 + cs);
        __builtin_amdgcn_s_setprio(1);
#pragma unroll
        for (int m = 0; m < 4; m++)
#pragma unroll
            for (int n = 0; n < 4; n++)
                acc[m][n] = __builtin_amdgcn_mfma_f32_16x16x32_bf16(b[n], a[m], acc[m][n], 0, 0, 0);
        __builtin_amdgcn_s_setprio(0);
        cur = (cur == 2) ? 0 : cur + 1;
    }
    const int rj = l4 * 4;
#pragma unroll
    for (int m = 0; m < 4; m++) {
        int lr2 = wr * 64 + m * 16 + l15;
        if (m0 + lr2 < cnt) {
            int slot = slot_s[lr2];
            unsigned short* hp = hbuf + (size_t)slot * ID + n0 + wc * 64 + rj;
#pragma unroll
            for (int n = 0; n < 4; n++) {
                uint2 pk;
                pk.x = cvt_pk_bf16(gelu_s(acc[m][n][0]), gelu_s(acc[m][n][1]));
                pk.y = cvt_pk_bf16(gelu_s(acc[m][n][2]), gelu_s(acc[m][n][3]));
                *(uint2*)(hp + n * 16) = pk;
            }
        }
    }
}

// GEMM2: pout[slot] = gate[slot] * (h_gathered @ w2[e]^T). K=3072, NK=96.
__launch_bounds__(512, 2)
__global__ void k_gemm2(const unsigned short* __restrict__ hbuf, const unsigned short* __restrict__ w2b,
                        const int* __restrict__ lists, const int* __restrict__ counts,
                        const float* __restrict__ gates, unsigned short* __restrict__ pout) {
    const int bsw = (blockIdx.x & 7) * (MAXB >> 3) + (blockIdx.x >> 3);
    int e, m0;
    decode_em(counts, bsw, e, m0);
    if (e < 0) return;
    const int cnt = counts[e];
    const int n0 = blockIdx.y * 128;
    __shared__ __align__(16) unsigned short As[3 * ASZ];
    __shared__ __align__(16) unsigned short Bs[3 * BSZ];
    __shared__ int slot_s[256];
    const int tid = threadIdx.x, lane = tid & 63, wid = tid >> 6;
    if (tid < 256) {
        int r = m0 + tid;
        slot_s[tid] = lists[e * NT + (r < cnt ? r : cnt - 1)];
    }
    __syncthreads();

    const int rsub = lane >> 2;
    const int sw = (((lane & 3) ^ ((rsub >> 1) & 3)) * 8);
    const int row0 = wid * 16 + rsub;
    const unsigned short* gA0 = hbuf + (size_t)slot_s[row0] * ID + sw;
    const unsigned short* gA1 = hbuf + (size_t)slot_s[row0 + 128] * ID + sw;
    const unsigned short* gB0 = w2b + ((size_t)e * HD + n0 + row0) * ID + sw;
    auto stage = [&](int bf) {
        gload16(gA0, As + bf * ASZ + wid * 512);       gA0 += BK;
        gload16(gA1, As + bf * ASZ + (wid + 8) * 512); gA1 += BK;
        gload16(gB0, Bs + bf * BSZ + wid * 512);       gB0 += BK;
    };

    const int wr = wid >> 1, wc = wid & 1;
    const int l15 = lane & 15, l4 = lane >> 4;
    const int aBase = (wr * 64 + l15) * BK;
    const int bBase = (wc * 64 + l15) * BK;
    const int cs = (l4 ^ ((l15 >> 1) & 3)) * 8;

    f32x4 acc[4][4];
    f32x4 zero = {0.f, 0.f, 0.f, 0.f};
#pragma unroll
    for (int m = 0; m < 4; m++)
#pragma unroll
        for (int n = 0; n < 4; n++) acc[m][n] = zero;

    const int NK = ID / BK;      // 96
    stage(0); stage(1);
    int cur = 0, pf = 2;
    for (int kt = 0; kt < NK; ++kt) {
        if (kt + 1 < NK) asm volatile("s_waitcnt vmcnt(3)\ns_barrier" ::: "memory");
        else             asm volatile("s_waitcnt vmcnt(0)\ns_barrier" ::: "memory");
        if (kt + 2 < NK) { stage(pf); pf = (pf == 2) ? 0 : pf + 1; }
        const unsigned short* Ab = As + cur * ASZ;
        const unsigned short* Bb = Bs + cur * BSZ;
        bf16x8 a[4], b[4];
#pragma unroll
        for (int m = 0; m < 4; m++) a[m] = *(const bf16x8*)(Ab + aBase + m * 512 + cs);
#pragma unroll
        for (int n = 0; n < 4; n++) b[n] = *(const bf16x8*)(Bb + bBase + n * 512 + cs);
        __builtin_amdgcn_s_setprio(1);
#pragma unroll
        for (int m = 0; m < 4; m++)
#pragma unroll
            for (int n = 0; n < 4; n++)
                acc[m][n] = __builtin_amdgcn_mfma_f32_16x16x32_bf16(b[n], a[m], acc[m][n], 0, 0, 0);
        __builtin_amdgcn_s_setprio(0);
        cur = (cur == 2) ? 0 : cur + 1;
    }
    const int rj = l4 * 4;
#pragma unroll
    for (int m = 0; m < 4; m++) {
        int lr2 = wr * 64 + m * 16 + l15;
        if (m0 + lr2 < cnt) {
            int slot = slot_s[lr2];
            float g = gates[slot];
            unsigned short* pp = pout + (size_t)slot * HD + n0 + wc * 64 + rj;
#pragma unroll
            for (int n = 0; n < 4; n++) {
                uint2 pk;
                pk.x = cvt_pk_bf16(g * acc[m][n][0], g * acc[m][n][1]);
                pk.y = cvt_pk_bf16(g * acc[m][n][2], g * acc[m][n][3]);
                *(uint2*)(pp + n * 16) = pk;
            }
        }
    }
}

// out[t] = pout[2t] + pout[2t+1] + bias   (pout is bf16)
__global__ void k_combine(const unsigned short* __restrict__ pout, const float* __restrict__ bias,
                          float4* __restrict__ out) {
    int idx = blockIdx.x * 256 + threadIdx.x;   // over NT*HD/4
    int t = idx / (HD / 4);
    int c = idx - t * (HD / 4);
    ushort4 a = ((const ushort4*)pout)[(size_t)t * (2 * HD / 4) + c];
    ushort4 b = ((const ushort4*)pout)[(size_t)t * (2 * HD / 4) + HD / 4 + c];
    float4 bb = ((const float4*)bias)[c];
    float4 r;
    r.x = bf2f(a.x) + bf2f(b.x) + bb.x;
    r.y = bf2f(a.y) + bf2f(b.y) + bb.y;
    r.z = bf2f(a.z) + bf2f(b.z) + bb.z;
    r.w = bf2f(a.w) + bf2f(b.w) + bb.w;
    out[idx] = r;
}

extern "C" void kernel_launch(void* const* d_in, const int* in_sizes, int n_in,
                              void* d_out, int out_size, void* d_ws, size_t ws_size,
                              hipStream_t stream) {
    const float* x    = (const float*)d_in[0];
    const float* rw   = (const float*)d_in[1];
    const float* w1   = (const float*)d_in[2];
    const float* w2   = (const float*)d_in[3];
    const float* bias = (const float*)d_in[4];
    float* out = (float*)d_out;

    char* ws = (char*)d_ws;
    size_t off = 0;
    auto alloc = [&](size_t bytes) -> char* {
        char* p = ws + off;
        off += (bytes + 255) & ~(size_t)255;
        return p;
    };
    int*            counts = (int*)alloc(NE * 4);
    int*            ccnt   = (int*)alloc(NE * 8 * 4);
    int*            lists  = (int*)alloc((size_t)NE * NT * 4);
    float*          gates  = (float*)alloc((size_t)NT * 2 * 4);
    uchar2*         choice = (uchar2*)alloc((size_t)NT * 2);
    unsigned short* xb     = (unsigned short*)alloc((size_t)NT * HD * 2);
    unsigned short* w1b    = (unsigned short*)alloc((size_t)NE * ID * HD * 2);
    unsigned short* w2b    = (unsigned short*)alloc((size_t)NE * HD * ID * 2);
    unsigned short* hbuf   = (unsigned short*)alloc((size_t)NT * 2 * ID * 2);
    unsigned short* pout   = (unsigned short*)alloc((size_t)NT * 2 * HD * 2);

    k_front<<<dim3(RT_BLOCKS + CW1_BLOCKS), dim3(256), 0, stream>>>(
        x, rw, (const float4*)w1, (ushort4*)w1b, (ushort4*)xb, gates, choice);
    k_cnt<<<dim3(64), dim3(256), 0, stream>>>(choice, ccnt);
    k_wr<<<dim3(64), dim3(256), 0, stream>>>(choice, ccnt, lists, counts);
    k_gemm1<<<dim3(G1_GEMM + CW2_BLOCKS), dim3(512), 0, stream>>>(
        xb, w1b, (const float4*)w2, (ushort4*)w2b, lists, counts, hbuf);
    k_gemm2<<<dim3(MAXB, HD / 128), dim3(512), 0, stream>>>(hbuf, w2b, lists, counts, gates, pout);
    k_combine<<<dim3(NT * HD / 4 / 256), dim3(256), 0, stream>>>(pout, bias, (float4*)out);
}

// Round 13
// 251.836 us; speedup vs baseline: 1.2734x; 1.0429x over previous
//
#include <hip/hip_runtime.h>
#include <hip/hip_bf16.h>
#include <math.h>

#define NT 8192
#define HD 768
#define ID 3072
#define NE 8
#define BK 32
#define MAXB 72     // >= sum_e ceil(cnt_e/256); 72 = 8*9 (bijective XCD swizzle)
#define ASZ (256 * BK)   // gemm1 A buffer (shorts)
#define BSZ (128 * BK)   // gemm1 B buffer (shorts)
#define TSZ (256 * BK)   // gemm2 ring-slot per operand (shorts, 16 KB)
#define RT_BLOCKS 256                         // router blocks (32 tokens each)
#define CW1_BLOCKS (NE * ID * HD / 4 / 1024)  // w1 convert blocks
#define G1_GEMM (MAXB * (ID / 128))           // 1728 gemm blocks in k_gemm1
#define CW2_BLOCKS (NE * HD * ID / 4 / 2048)  // w2 convert blocks (512 thr)

typedef __bf16 bf16x8 __attribute__((ext_vector_type(8)));
typedef float f32x4 __attribute__((ext_vector_type(4)));

__device__ __forceinline__ unsigned short f2bf(float f) {
    union { float f; unsigned u; } v; v.f = f;
    unsigned r = v.u + 0x7FFFu + ((v.u >> 16) & 1u);   // RNE
    return (unsigned short)(r >> 16);
}
__device__ __forceinline__ float bf2f(unsigned short b) {
    union { unsigned u; float f; } v; v.u = ((unsigned)b) << 16;
    return v.f;
}
__device__ __forceinline__ unsigned cvt_pk_bf16(float lo, float hi) {
    unsigned r;
    asm("v_cvt_pk_bf16_f32 %0, %1, %2" : "=v"(r) : "v"(lo), "v"(hi));
    return r;
}
// gelu(tanh form) == v * sigmoid(2u). 1 exp + 1 rcp.
__device__ __forceinline__ float gelu_s(float v) {
    float z = v * (1.5957691216057308f + 0.07135481283687945f * v * v);
    float e = __expf(-z);
    return v * __builtin_amdgcn_rcpf(1.0f + e);
}

// global->LDS direct copy, 16B/lane. LDS dest = wave-uniform base + lane*16.
__device__ __forceinline__ void gload16(const void* g, void* l) {
    auto* lds = reinterpret_cast<__attribute__((address_space(3))) unsigned int*>(
        reinterpret_cast<uintptr_t>(l));
    auto* gp = reinterpret_cast<const __attribute__((address_space(1))) unsigned int*>(
        reinterpret_cast<uintptr_t>(g));
    __builtin_amdgcn_global_load_lds(gp, lds, 16, 0, 0);
}

// expert/m0 decode from counts for 256-row m-tiles (both GEMMs).
__device__ __forceinline__ void decode_em(const int* counts, int bsw, int& e, int& m0) {
    e = -1; m0 = 0;
    int s = 0;
#pragma unroll
    for (int q = 0; q < NE; q++) {
        int nb = (counts[q] + 255) >> 8;
        if (bsw >= s && bsw < s + nb) { e = q; m0 = (bsw - s) << 8; }
        s += nb;
    }
}

// Fused front: blocks [0,RT_BLOCKS) = router; rest = w1 fp32->bf16 convert.
__global__ void k_front(const float* __restrict__ x, const float* __restrict__ rw,
                        const float4* __restrict__ w1, ushort4* __restrict__ w1b,
                        ushort4* __restrict__ xb4, float* __restrict__ gates,
                        uchar2* __restrict__ choice) {
    __shared__ float rws[NE * HD];
    const int tid = threadIdx.x;
    if (blockIdx.x >= RT_BLOCKS) {
        int base = (blockIdx.x - RT_BLOCKS) * 1024 + tid;
#pragma unroll
        for (int i = 0; i < 4; i++) {
            int idx = base + i * 256;
            float4 a = w1[idx];
            ushort4 ra;
            ra.x = f2bf(a.x); ra.y = f2bf(a.y); ra.z = f2bf(a.z); ra.w = f2bf(a.w);
            w1b[idx] = ra;
        }
        return;
    }
    for (int i = tid; i < NE * HD / 4; i += 256)
        ((float4*)rws)[i] = ((const float4*)rw)[i];
    __syncthreads();
    const int wid = tid >> 6, lane = tid & 63;
    const float4* rws4 = (const float4*)rws;
    for (int it = 0; it < 8; ++it) {
        const int t = blockIdx.x * 32 + wid * 8 + it;
        const float4* xp4 = (const float4*)(x + (size_t)t * HD);
        float acc[NE];
#pragma unroll
        for (int e = 0; e < NE; e++) acc[e] = 0.f;
#pragma unroll
        for (int j = 0; j < HD / 256; j++) {
            float4 v = xp4[lane + 64 * j];
            ushort4 o;
            o.x = f2bf(v.x); o.y = f2bf(v.y); o.z = f2bf(v.z); o.w = f2bf(v.w);
            xb4[(size_t)t * (HD / 4) + lane + 64 * j] = o;
#pragma unroll
            for (int e = 0; e < NE; e++) {
                float4 w = rws4[e * (HD / 4) + lane + 64 * j];
                acc[e] += v.x * w.x + v.y * w.y + v.z * w.z + v.w * w.w;
            }
        }
#pragma unroll
        for (int e = 0; e < NE; e++)
            for (int off = 32; off; off >>= 1) acc[e] += __shfl_xor(acc[e], off);
        if (lane == 0) {
            float mx = acc[0];
#pragma unroll
            for (int e = 1; e < NE; e++) mx = fmaxf(mx, acc[e]);
            float p[NE], s = 0.f;
#pragma unroll
            for (int e = 0; e < NE; e++) { p[e] = __expf(acc[e] - mx); s += p[e]; }
            float inv = 1.f / s;
            int i1 = 0; float b1 = p[0];
#pragma unroll
            for (int e = 1; e < NE; e++) if (p[e] > b1) { b1 = p[e]; i1 = e; }
            int i2 = (i1 == 0) ? 1 : 0; float b2 = p[i2];
#pragma unroll
            for (int e = 0; e < NE; e++) if (e != i1 && p[e] > b2) { b2 = p[e]; i2 = e; }
            choice[t].x = (unsigned char)i1;
            choice[t].y = (unsigned char)i2;
            gates[2 * t] = b1 * inv;
            gates[2 * t + 1] = b2 * inv;
        }
    }
}

// Scatter phase A: 64 blocks = (expert, 1024-token chunk); ballot count. No atomics.
__global__ void k_cnt(const uchar2* __restrict__ choice, int* __restrict__ ccnt) {
    const int e = blockIdx.x >> 3, c = blockIdx.x & 7;
    const int tid = threadIdx.x, wid = tid >> 6, lane = tid & 63;
    __shared__ int ws[4];
    int tot = 0;
#pragma unroll
    for (int p = 0; p < 4; p++) {
        int t = c * 1024 + p * 256 + tid;
        uchar2 ch = choice[t];
        bool m = (ch.x == e) || (ch.y == e);
        unsigned long long mask = __ballot(m);
        if (lane == 0) tot += __popcll(mask);
    }
    if (lane == 0) ws[wid] = tot;
    __syncthreads();
    if (tid == 0) ccnt[blockIdx.x] = ws[0] + ws[1] + ws[2] + ws[3];
}

// Scatter phase B: prefix over ccnt then ballot-scan write. No atomics.
__global__ void k_wr(const uchar2* __restrict__ choice, const int* __restrict__ ccnt,
                     int* __restrict__ lists, int* __restrict__ counts) {
    const int e = blockIdx.x >> 3, c = blockIdx.x & 7;
    const int tid = threadIdx.x, wid = tid >> 6, lane = tid & 63;
    __shared__ int wtot[4];
    __shared__ int running;
    if (tid == 0) {
        int b = 0;
        for (int q = 0; q < c; q++) b += ccnt[e * 8 + q];
        running = b;
        if (c == 7) counts[e] = b + ccnt[e * 8 + 7];
    }
    __syncthreads();
#pragma unroll
    for (int p = 0; p < 4; p++) {
        int t = c * 1024 + p * 256 + tid;
        uchar2 ch = choice[t];
        bool m1 = (ch.x == e), m2 = (ch.y == e);
        bool m = m1 || m2;
        int slot = m1 ? 2 * t : 2 * t + 1;
        unsigned long long mask = __ballot(m);
        int off = __popcll(mask & ((1ULL << lane) - 1ULL));
        if (lane == 0) wtot[wid] = __popcll(mask);
        __syncthreads();
        int base = running;
        for (int w = 0; w < wid; w++) base += wtot[w];
        if (m) lists[e * NT + base + off] = slot;
        __syncthreads();
        if (tid == 0) running += wtot[0] + wtot[1] + wtot[2] + wtot[3];
        __syncthreads();
    }
}

// GEMM1 (round-12 proven config, unchanged): 256x128 tile, 8 waves 4Mx2N, BK=32,
// 3 buffers, vmcnt(3), swizzled LDS, setprio MFMA, gelu epilogue + w2-convert
// backfill in trailing blocks.
__launch_bounds__(512, 2)
__global__ void k_gemm1(const unsigned short* __restrict__ xb, const unsigned short* __restrict__ w1b,
                        const float4* __restrict__ w2, ushort4* __restrict__ w2b,
                        const int* __restrict__ lists, const int* __restrict__ counts,
                        unsigned short* __restrict__ hbuf) {
    const int tid = threadIdx.x;
    if (blockIdx.x >= G1_GEMM) {
        int base = (blockIdx.x - G1_GEMM) * 2048 + tid;
#pragma unroll
        for (int i = 0; i < 4; i++) {
            int idx = base + i * 512;
            float4 a = w2[idx];
            ushort4 ra;
            ra.x = f2bf(a.x); ra.y = f2bf(a.y); ra.z = f2bf(a.z); ra.w = f2bf(a.w);
            w2b[idx] = ra;
        }
        return;
    }
    const int mi = blockIdx.x % MAXB;
    const int ny = blockIdx.x / MAXB;
    const int bsw = (mi & 7) * (MAXB >> 3) + (mi >> 3);
    int e, m0;
    decode_em(counts, bsw, e, m0);
    if (e < 0) return;
    const int cnt = counts[e];
    const int n0 = ny * 128;
    __shared__ __align__(16) unsigned short As[3 * ASZ];
    __shared__ __align__(16) unsigned short Bs[3 * BSZ];
    __shared__ int slot_s[256];
    const int lane = tid & 63, wid = tid >> 6;
    if (tid < 256) {
        int r = m0 + tid;
        slot_s[tid] = lists[e * NT + (r < cnt ? r : cnt - 1)];
    }
    __syncthreads();

    const int rsub = lane >> 2;
    const int sw = (((lane & 3) ^ ((rsub >> 1) & 3)) * 8);
    const int row0 = wid * 16 + rsub;
    const unsigned short* gA0 = xb + (size_t)(slot_s[row0] >> 1) * HD + sw;
    const unsigned short* gA1 = xb + (size_t)(slot_s[row0 + 128] >> 1) * HD + sw;
    const unsigned short* gB0 = w1b + ((size_t)e * ID + n0 + row0) * HD + sw;
    auto stage = [&](int bf) {
        gload16(gA0, As + bf * ASZ + wid * 512);       gA0 += BK;
        gload16(gA1, As + bf * ASZ + (wid + 8) * 512); gA1 += BK;
        gload16(gB0, Bs + bf * BSZ + wid * 512);       gB0 += BK;
    };

    const int wr = wid >> 1, wc = wid & 1;
    const int l15 = lane & 15, l4 = lane >> 4;
    const int aBase = (wr * 64 + l15) * BK;
    const int bBase = (wc * 64 + l15) * BK;
    const int cs = (l4 ^ ((l15 >> 1) & 3)) * 8;

    f32x4 acc[4][4];
    f32x4 zero = {0.f, 0.f, 0.f, 0.f};
#pragma unroll
    for (int m = 0; m < 4; m++)
#pragma unroll
        for (int n = 0; n < 4; n++) acc[m][n] = zero;

    const int NK = HD / BK;      // 24
    stage(0); stage(1);
    int cur = 0, pf = 2;
    for (int kt = 0; kt < NK; ++kt) {
        if (kt + 1 < NK) asm volatile("s_waitcnt vmcnt(3)\ns_barrier" ::: "memory");
        else             asm volatile("s_waitcnt vmcnt(0)\ns_barrier" ::: "memory");
        if (kt + 2 < NK) { stage(pf); pf = (pf == 2) ? 0 : pf + 1; }
        const unsigned short* Ab = As + cur * ASZ;
        const unsigned short* Bb = Bs + cur * BSZ;
        bf16x8 a[4], b[4];
#pragma unroll
        for (int m = 0; m < 4; m++) a[m] = *(const bf16x8*)(Ab + aBase + m * 512 + cs);
#pragma unroll
        for (int n = 0; n < 4; n++) b[n] = *(const bf16x8*)(Bb + bBase + n * 512 + cs);
        __builtin_amdgcn_s_setprio(1);
#pragma unroll
        for (int m = 0; m < 4; m++)
#pragma unroll
            for (int n = 0; n < 4; n++)
                acc[m][n] = __builtin_amdgcn_mfma_f32_16x16x32_bf16(b[n], a[m], acc[m][n], 0, 0, 0);
        __builtin_amdgcn_s_setprio(0);
        cur = (cur == 2) ? 0 : cur + 1;
    }
    const int rj = l4 * 4;
#pragma unroll
    for (int m = 0; m < 4; m++) {
        int lr2 = wr * 64 + m * 16 + l15;
        if (m0 + lr2 < cnt) {
            int slot = slot_s[lr2];
            unsigned short* hp = hbuf + (size_t)slot * ID + n0 + wc * 64 + rj;
#pragma unroll
            for (int n = 0; n < 4; n++) {
                uint2 pk;
                pk.x = cvt_pk_bf16(gelu_s(acc[m][n][0]), gelu_s(acc[m][n][1]));
                pk.y = cvt_pk_bf16(gelu_s(acc[m][n][2]), gelu_s(acc[m][n][3]));
                *(uint2*)(hp + n * 16) = pk;
            }
        }
    }
}

// GEMM2: phase-split 256x256 template. 8 waves (2M x 4N), wave tile 128x64,
// acc[8][4], BK=32 sub-tiles in a ring of 4 LDS buffers (128 KB, 1 block/CU).
// Per sub-tile st: phase A {read b[0..3],a[0..3]; stage A(st+2); 16 MFMA; barrier}
// phase B {read a[4..7]; stage B(st+2); 16 MFMA; vmcnt(4); barrier}.
// RAW: ring[st] staged during st-2, retired by end-of-(st-1) vmcnt(4).
// WAR: ring[(st+2)&3] old content consumed two barriers earlier. Tail: vmcnt(0).
__launch_bounds__(512, 2)
__global__ void k_gemm2(const unsigned short* __restrict__ hbuf, const unsigned short* __restrict__ w2b,
                        const int* __restrict__ lists, const int* __restrict__ counts,
                        const float* __restrict__ gates, unsigned short* __restrict__ pout) {
    const int bsw = (blockIdx.x & 7) * (MAXB >> 3) + (blockIdx.x >> 3);
    int e, m0;
    decode_em(counts, bsw, e, m0);
    if (e < 0) return;
    const int cnt = counts[e];
    const int n0 = blockIdx.y * 256;
    __shared__ __align__(16) unsigned short As[4 * TSZ];   // 64 KB
    __shared__ __align__(16) unsigned short Bs[4 * TSZ];   // 64 KB
    __shared__ int slot_s[256];
    const int tid = threadIdx.x, lane = tid & 63, wid = tid >> 6;
    if (tid < 256) {
        int r = m0 + tid;
        slot_s[tid] = lists[e * NT + (r < cnt ? r : cnt - 1)];
    }
    __syncthreads();

    const int rsub = lane >> 2;
    const int sw = (((lane & 3) ^ ((rsub >> 1) & 3)) * 8);
    const int row0 = wid * 16 + rsub;
    const unsigned short* gA0 = hbuf + (size_t)slot_s[row0] * ID + sw;
    const unsigned short* gA1 = hbuf + (size_t)slot_s[row0 + 128] * ID + sw;
    const unsigned short* gB0 = w2b + ((size_t)e * HD + n0 + row0) * ID + sw;
    const unsigned short* gB1 = w2b + ((size_t)e * HD + n0 + row0 + 128) * ID + sw;
    auto stageA = [&](int bf) {
        gload16(gA0, As + bf * TSZ + wid * 512);       gA0 += BK;
        gload16(gA1, As + bf * TSZ + (wid + 8) * 512); gA1 += BK;
    };
    auto stageB = [&](int bf) {
        gload16(gB0, Bs + bf * TSZ + wid * 512);       gB0 += BK;
        gload16(gB1, Bs + bf * TSZ + (wid + 8) * 512); gB1 += BK;
    };

    const int wr = wid >> 2, wc = wid & 3;          // 2M x 4N
    const int l15 = lane & 15, l4 = lane >> 4;
    const int aBase = (wr * 128 + l15) * BK;
    const int bBase = (wc * 64 + l15) * BK;
    const int cs = (l4 ^ ((l15 >> 1) & 3)) * 8;

    f32x4 acc[8][4];
    f32x4 zero = {0.f, 0.f, 0.f, 0.f};
#pragma unroll
    for (int m = 0; m < 8; m++)
#pragma unroll
        for (int n = 0; n < 4; n++) acc[m][n] = zero;

    const int NK = ID / BK;      // 96
    stageA(0); stageB(0); stageA(1); stageB(1);     // 8 issues: st0 oldest
    asm volatile("s_waitcnt vmcnt(4)\ns_barrier" ::: "memory");  // st0 landed
    for (int st = 0; st < NK; ++st) {
        const unsigned short* Ab = As + (st & 3) * TSZ;
        const unsigned short* Bb = Bs + (st & 3) * TSZ;
        // ---- phase A: b-frags + a[0..3], stage A(st+2), MFMA quadrant m0..3
        bf16x8 b[4], a[4];
#pragma unroll
        for (int n = 0; n < 4; n++) b[n] = *(const bf16x8*)(Bb + bBase + n * 512 + cs);
#pragma unroll
        for (int m = 0; m < 4; m++) a[m] = *(const bf16x8*)(Ab + aBase + m * 512 + cs);
        if (st + 2 < NK) stageA((st + 2) & 3);
        __builtin_amdgcn_s_setprio(1);
#pragma unroll
        for (int m = 0; m < 4; m++)
#pragma unroll
            for (int n = 0; n < 4; n++)
                acc[m][n] = __builtin_amdgcn_mfma_f32_16x16x32_bf16(b[n], a[m], acc[m][n], 0, 0, 0);
        __builtin_amdgcn_s_setprio(0);
        asm volatile("s_barrier" ::: "memory");
        // ---- phase B: a[4..7], stage B(st+2), MFMA quadrant m4..7
        bf16x8 a2[4];
#pragma unroll
        for (int m = 0; m < 4; m++) a2[m] = *(const bf16x8*)(Ab + aBase + (m + 4) * 512 + cs);
        if (st + 2 < NK) stageB((st + 2) & 3);
        __builtin_amdgcn_s_setprio(1);
#pragma unroll
        for (int m = 0; m < 4; m++)
#pragma unroll
            for (int n = 0; n < 4; n++)
                acc[m + 4][n] = __builtin_amdgcn_mfma_f32_16x16x32_bf16(b[n], a2[m], acc[m + 4][n], 0, 0, 0);
        __builtin_amdgcn_s_setprio(0);
        if (st + 2 < NK) asm volatile("s_waitcnt vmcnt(4)\ns_barrier" ::: "memory");
        else             asm volatile("s_waitcnt vmcnt(0)\ns_barrier" ::: "memory");
    }
    const int rj = l4 * 4;
#pragma unroll
    for (int m = 0; m < 8; m++) {
        int lr2 = wr * 128 + m * 16 + l15;
        if (m0 + lr2 < cnt) {
            int slot = slot_s[lr2];
            float g = gates[slot];
            unsigned short* pp = pout + (size_t)slot * HD + n0 + wc * 64 + rj;
#pragma unroll
            for (int n = 0; n < 4; n++) {
                uint2 pk;
                pk.x = cvt_pk_bf16(g * acc[m][n][0], g * acc[m][n][1]);
                pk.y = cvt_pk_bf16(g * acc[m][n][2], g * acc[m][n][3]);
                *(uint2*)(pp + n * 16) = pk;
            }
        }
    }
}

// out[t] = pout[2t] + pout[2t+1] + bias   (pout is bf16)
__global__ void k_combine(const unsigned short* __restrict__ pout, const float* __restrict__ bias,
                          float4* __restrict__ out) {
    int idx = blockIdx.x * 256 + threadIdx.x;   // over NT*HD/4
    int t = idx / (HD / 4);
    int c = idx - t * (HD / 4);
    ushort4 a = ((const ushort4*)pout)[(size_t)t * (2 * HD / 4) + c];
    ushort4 b = ((const ushort4*)pout)[(size_t)t * (2 * HD / 4) + HD / 4 + c];
    float4 bb = ((const float4*)bias)[c];
    float4 r;
    r.x = bf2f(a.x) + bf2f(b.x) + bb.x;
    r.y = bf2f(a.y) + bf2f(b.y) + bb.y;
    r.z = bf2f(a.z) + bf2f(b.z) + bb.z;
    r.w = bf2f(a.w) + bf2f(b.w) + bb.w;
    out[idx] = r;
}

extern "C" void kernel_launch(void* const* d_in, const int* in_sizes, int n_in,
                              void* d_out, int out_size, void* d_ws, size_t ws_size,
                              hipStream_t stream) {
    const float* x    = (const float*)d_in[0];
    const float* rw   = (const float*)d_in[1];
    const float* w1   = (const float*)d_in[2];
    const float* w2   = (const float*)d_in[3];
    const float* bias = (const float*)d_in[4];
    float* out = (float*)d_out;

    char* ws = (char*)d_ws;
    size_t off = 0;
    auto alloc = [&](size_t bytes) -> char* {
        char* p = ws + off;
        off += (bytes + 255) & ~(size_t)255;
        return p;
    };
    int*            counts = (int*)alloc(NE * 4);
    int*            ccnt   = (int*)alloc(NE * 8 * 4);
    int*            lists  = (int*)alloc((size_t)NE * NT * 4);
    float*          gates  = (float*)alloc((size_t)NT * 2 * 4);
    uchar2*         choice = (uchar2*)alloc((size_t)NT * 2);
    unsigned short* xb     = (unsigned short*)alloc((size_t)NT * HD * 2);
    unsigned short* w1b    = (unsigned short*)alloc((size_t)NE * ID * HD * 2);
    unsigned short* w2b    = (unsigned short*)alloc((size_t)NE * HD * ID * 2);
    unsigned short* hbuf   = (unsigned short*)alloc((size_t)NT * 2 * ID * 2);
    unsigned short* pout   = (unsigned short*)alloc((size_t)NT * 2 * HD * 2);

    k_front<<<dim3(RT_BLOCKS + CW1_BLOCKS), dim3(256), 0, stream>>>(
        x, rw, (const float4*)w1, (ushort4*)w1b, (ushort4*)xb, gates, choice);
    k_cnt<<<dim3(64), dim3(256), 0, stream>>>(choice, ccnt);
    k_wr<<<dim3(64), dim3(256), 0, stream>>>(choice, ccnt, lists, counts);
    k_gemm1<<<dim3(G1_GEMM + CW2_BLOCKS), dim3(512), 0, stream>>>(
        xb, w1b, (const float4*)w2, (ushort4*)w2b, lists, counts, hbuf);
    k_gemm2<<<dim3(MAXB, HD / 256), dim3(512), 0, stream>>>(hbuf, w2b, lists, counts, gates, pout);
    k_combine<<<dim3(NT * HD / 4 / 256), dim3(256), 0, stream>>>(pout, bias, (float4*)out);
}